// Round 1
// baseline (3473.342 us; speedup 1.0000x reference)
//
#include <hip/hip_runtime.h>
#include <math.h>

// ---------------- problem constants ----------------
#define NCAM 6
#define IH 256
#define IW 704
#define FH 32
#define FW 88
#define DD 59
#define CIMG 80
#define NXv 360
#define PIX (FH*FW)           // 2816
#define IMGPIX (IH*IW)        // 180224
#define NPTS (NCAM*DD*PIX)    // 996864

// ---------------- ws arena offsets (in floats) ----------------
// persistent
#define OFF_MATS 0                      // 144
#define OFF_TW1  144                    // 57600
#define OFF_TW2  57744                  // 57600
// SEG_A: h1 (8,650,752) -> f2 (4,325,376) -> pooled (10,368,000)
#define OFF_A    115344
// SEG_B: h2 (2,162,688) -> f3 (2,348,544)
#define OFF_B    10483344
// SEG_C: h3 (1,081,344) -> depth (996,864)
#define OFF_C    12831888
// SEG_D: f1 (4,325,376) -> featT (1,351,680) + flat (996,864) + bev1 (2,592,000)
#define OFF_D      13913232
#define OFF_FEATT  OFF_D
#define OFF_FLAT   (OFF_D + 1351680)
#define OFF_BEV1   (OFF_D + 2348544)
// total: 18,853,776 floats = ~75.4 MB

// ---------------- small helpers ----------------
__device__ __forceinline__ void inv3(const float* m, float* o) {
    float a=m[0],b=m[1],c=m[2],d=m[3],e=m[4],f=m[5],g=m[6],h=m[7],i=m[8];
    float A =  (e*i - f*h);
    float B = -(d*i - f*g);
    float C =  (d*h - e*g);
    float det = a*A + b*B + c*C;
    float r = 1.f/det;
    o[0]=A*r;            o[1]=-(b*i - c*h)*r; o[2]=(b*f - c*e)*r;
    o[3]=B*r;            o[4]=(a*i - c*g)*r;  o[5]=-(a*f - c*d)*r;
    o[6]=C*r;            o[7]=-(a*h - b*g)*r; o[8]=(a*e - b*d)*r;
}

// per-camera composed transforms: A(9), b0(3), comb(9), t(3) = 24 floats
__global__ void k_cam_mats(const float* __restrict__ prot, const float* __restrict__ ptran,
                           const float* __restrict__ intr, const float* __restrict__ Rcl,
                           const float* __restrict__ tcl, float* __restrict__ mats) {
    int n = threadIdx.x;
    if (n >= NCAM) return;
    float P[9], Km[9], R[9], A[9], Ki[9];
    for (int i=0;i<9;i++){ P[i]=prot[n*9+i]; Km[i]=intr[n*9+i]; R[i]=Rcl[n*9+i]; }
    inv3(P, A); inv3(Km, Ki);
    float* M = mats + n*24;
    for (int i=0;i<9;i++) M[i] = A[i];
    for (int r=0;r<3;r++)
        M[9+r] = -(A[r*3+0]*ptran[n*3+0] + A[r*3+1]*ptran[n*3+1] + A[r*3+2]*ptran[n*3+2]);
    for (int r=0;r<3;r++) for (int c=0;c<3;c++)
        M[12 + r*3+c] = R[r*3+0]*Ki[0*3+c] + R[r*3+1]*Ki[1*3+c] + R[r*3+2]*Ki[2*3+c];
    for (int r=0;r<3;r++) M[21+r] = tcl[n*3+r];
}

// transpose [80,80,3,3] -> [3,3,80(ci),80(co)]
__global__ void k_wtrans(const float* __restrict__ w, float* __restrict__ tw) {
    int i = blockIdx.x*blockDim.x + threadIdx.x;
    if (i >= CIMG*CIMG*9) return;
    int kw = i % 3; int r = i/3;
    int kh = r % 3; r /= 3;
    int ci = r % CIMG; int co = r / CIMG;
    tw[((kh*3+kw)*CIMG + ci)*CIMG + co] = w[i];
}

// dtransform conv1: 1x1, 1->8, + bias, BN, ReLU
__global__ __launch_bounds__(256) void k_dt1(const float* __restrict__ d, const float* __restrict__ w,
                                             const float* __restrict__ b, const float* __restrict__ s,
                                             const float* __restrict__ t, float* __restrict__ out) {
    int i = blockIdx.x*256 + threadIdx.x;      // over 6*256*704
    if (i >= NCAM*IMGPIX) return;
    int n = i / IMGPIX;
    int yx = i % IMGPIX;
    float v = d[i];
    #pragma unroll
    for (int c=0;c<8;c++) {
        float r = fmaxf(fmaf(fmaf(v, w[c], b[c]), s[c], t[c]), 0.f);
        out[(size_t)(n*8+c)*IMGPIX + yx] = r;
    }
}

// dtransform conv2: 5x5 s4 p2, 8->32 : [6,8,256,704] -> [6,32,64,176]
__global__ __launch_bounds__(256) void k_dt2(const float* __restrict__ in, const float* __restrict__ w,
                                             const float* __restrict__ b, const float* __restrict__ s,
                                             const float* __restrict__ t, float* __restrict__ out) {
    const int co = blockIdx.y, n = blockIdx.z;
    int o = blockIdx.x*256 + threadIdx.x;      // 64*176 = 11264
    int yo = o / 176, xo = o % 176;
    float acc = b[co];
    const float* wp = w + co*8*25;
    int yi0 = yo*4-2, xi0 = xo*4-2;
    for (int ci=0; ci<8; ci++) {
        const float* ip = in + (size_t)(n*8+ci)*IMGPIX;
        #pragma unroll
        for (int ky=0;ky<5;ky++) {
            int yi = yi0+ky;
            bool yv = ((unsigned)yi < IH);
            #pragma unroll
            for (int kx=0;kx<5;kx++) {
                int xi = xi0+kx;
                float v = (yv && ((unsigned)xi < IW)) ? ip[yi*IW+xi] : 0.f;
                acc = fmaf(v, wp[ci*25+ky*5+kx], acc);
            }
        }
    }
    out[((size_t)(n*32+co)*64+yo)*176+xo] = fmaxf(fmaf(acc, s[co], t[co]), 0.f);
}

// dtransform conv3: 5x5 s2 p2, 32->64 : [6,32,64,176] -> [6,64,32,88]
__global__ __launch_bounds__(256) void k_dt3(const float* __restrict__ in, const float* __restrict__ w,
                                             const float* __restrict__ b, const float* __restrict__ s,
                                             const float* __restrict__ t, float* __restrict__ out) {
    const int co = blockIdx.y, n = blockIdx.z;
    int o = blockIdx.x*256 + threadIdx.x;      // 32*88 = 2816
    int yo = o / FW, xo = o % FW;
    float acc = b[co];
    const float* wp = w + co*32*25;
    int yi0 = yo*2-2, xi0 = xo*2-2;
    for (int ci=0; ci<32; ci++) {
        const float* ip = in + (size_t)(n*32+ci)*(64*176);
        #pragma unroll
        for (int ky=0;ky<5;ky++) {
            int yi = yi0+ky;
            bool yv = ((unsigned)yi < 64);
            #pragma unroll
            for (int kx=0;kx<5;kx++) {
                int xi = xi0+kx;
                float v = (yv && ((unsigned)xi < 176)) ? ip[yi*176+xi] : 0.f;
                acc = fmaf(v, wp[ci*25+ky*5+kx], acc);
            }
        }
    }
    out[((size_t)(n*64+co)*FH+yo)*FW+xo] = fmaxf(fmaf(acc, s[co], t[co]), 0.f);
}

// generic 3x3 pad1 conv on 32x88, cin = C1 (+C2 concat), 4 output channels per thread,
// + bias + BN + ReLU
template<int C1, int C2, int COUT>
__global__ __launch_bounds__(256) void k_conv3x3(const float* __restrict__ src1,
                                                 const float* __restrict__ src2,
                                                 const float* __restrict__ w,
                                                 const float* __restrict__ b,
                                                 const float* __restrict__ s,
                                                 const float* __restrict__ t,
                                                 float* __restrict__ out) {
    const int CK = (C1+C2)*9;
    const int n = blockIdx.z;
    const int co0 = blockIdx.y*4;
    int o = blockIdx.x*256 + threadIdx.x;       // 0..2815
    int y = o / FW, x = o % FW;
    float acc0 = b[co0+0], acc1 = b[co0+1], acc2 = b[co0+2], acc3 = b[co0+3];
    const float* wb = w + (size_t)co0*CK;
    for (int ci=0; ci<C1+C2; ci++) {
        const float* ip;
        if (C2 == 0) ip = src1 + (size_t)(n*C1+ci)*PIX;
        else ip = (ci < C1) ? (src1 + (size_t)(n*C1+ci)*PIX)
                            : (src2 + (size_t)(n*C2+(ci-C1))*PIX);
        float v[9];
        #pragma unroll
        for (int ky=0;ky<3;ky++) {
            int yy = y-1+ky;
            bool yv = ((unsigned)yy < FH);
            #pragma unroll
            for (int kx=0;kx<3;kx++) {
                int xx = x-1+kx;
                v[ky*3+kx] = (yv && ((unsigned)xx < FW)) ? ip[yy*FW+xx] : 0.f;
            }
        }
        const float* wp = wb + ci*9;
        #pragma unroll
        for (int k=0;k<9;k++) {
            acc0 = fmaf(v[k], wp[k],        acc0);
            acc1 = fmaf(v[k], wp[CK+k],     acc1);
            acc2 = fmaf(v[k], wp[2*CK+k],   acc2);
            acc3 = fmaf(v[k], wp[3*CK+k],   acc3);
        }
    }
    float* op = out + ((size_t)n*COUT + co0)*PIX + o;
    op[0]         = fmaxf(fmaf(acc0, s[co0+0], t[co0+0]), 0.f);
    op[PIX]       = fmaxf(fmaf(acc1, s[co0+1], t[co0+1]), 0.f);
    op[2*(size_t)PIX] = fmaxf(fmaf(acc2, s[co0+2], t[co0+2]), 0.f);
    op[3*(size_t)PIX] = fmaxf(fmaf(acc3, s[co0+3], t[co0+3]), 0.f);
}

// dn3: 1x1 conv 256->139 + bias (no BN/ReLU)
__global__ __launch_bounds__(256) void k_dn3(const float* __restrict__ in, const float* __restrict__ w,
                                             const float* __restrict__ b, float* __restrict__ out) {
    int o = blockIdx.x*256 + threadIdx.x;       // 2816
    int n = blockIdx.z;
    int co0 = blockIdx.y*4;                      // 0..136 (35 groups)
    const float* ip = in + (size_t)n*256*PIX + o;
    const float* w0 = w + (size_t)min(co0+0,138)*256;
    const float* w1 = w + (size_t)min(co0+1,138)*256;
    const float* w2 = w + (size_t)min(co0+2,138)*256;
    const float* w3 = w + (size_t)min(co0+3,138)*256;
    float a0=0.f,a1=0.f,a2=0.f,a3=0.f;
    for (int ci=0; ci<256; ci++) {
        float v = ip[(size_t)ci*PIX];
        a0 = fmaf(v, w0[ci], a0);
        a1 = fmaf(v, w1[ci], a1);
        a2 = fmaf(v, w2[ci], a2);
        a3 = fmaf(v, w3[ci], a3);
    }
    float acc[4] = {a0,a1,a2,a3};
    #pragma unroll
    for (int j=0;j<4;j++) {
        int co = co0+j;
        if (co < 139) out[((size_t)n*139+co)*PIX + o] = acc[j] + b[co];
    }
}

// softmax over first 59 channels -> depth [n,d,yx]; copy 80 img feats -> featT [n*PIX, 80]
__global__ __launch_bounds__(256) void k_softmax_feat(const float* __restrict__ f3,
                                                      float* __restrict__ depth,
                                                      float* __restrict__ featT) {
    int o = blockIdx.x*256 + threadIdx.x;       // 6*2816 = 16896
    int n = o / PIX, yx = o % PIX;
    const float* fp = f3 + (size_t)n*139*PIX + yx;
    float m = -1e30f;
    for (int d=0; d<DD; d++) m = fmaxf(m, fp[(size_t)d*PIX]);
    float sum = 0.f;
    for (int d=0; d<DD; d++) sum += expf(fp[(size_t)d*PIX]-m);
    float inv = 1.f/sum;
    for (int d=0; d<DD; d++)
        depth[((size_t)n*DD+d)*PIX + yx] = expf(fp[(size_t)d*PIX]-m)*inv;
    float* ft = featT + (size_t)o*CIMG;
    for (int c=0; c<CIMG; c++) ft[c] = fp[(size_t)(DD+c)*PIX];
}

// frustum -> lidar -> voxel index (or -1)
__global__ __launch_bounds__(256) void k_voxel(const float* __restrict__ mats, int* __restrict__ flat) {
    int p = blockIdx.x*256 + threadIdx.x;
    if (p >= NPTS) return;
    int x = p % FW; int t1 = p / FW;
    int y = t1 % FH; int t2 = t1 / FH;
    int dd = t2 % DD; int n = t2 / DD;
    float xf = x * (703.f/87.f);
    float yf = y * (255.f/31.f);
    float df = 1.f + (float)dd;
    const float* M = mats + n*24;
    float qx = M[0]*xf + M[1]*yf + M[2]*df + M[9];
    float qy = M[3]*xf + M[4]*yf + M[5]*df + M[10];
    float qz = M[6]*xf + M[7]*yf + M[8]*df + M[11];
    float rx = qx*qz, ry = qy*qz, rz = qz;
    float wx = M[12]*rx + M[13]*ry + M[14]*rz + M[21];
    float wy = M[15]*rx + M[16]*ry + M[17]*rz + M[22];
    float wz = M[18]*rx + M[19]*ry + M[20]*rz + M[23];
    int gx = (int)((wx + 54.f) / 0.3f);       // trunc toward zero (matches .astype(int32))
    int gy = (int)((wy + 54.f) / 0.3f);
    int gz = (int)((wz + 10.f) / 20.f);
    bool kept = ((unsigned)gx < NXv) && ((unsigned)gy < NXv) && (gz == 0);
    flat[p] = kept ? (gx*NXv + gy) : -1;      // b=0, gz=0
}

// scatter: pooled[cell,c] += depth[p] * featT[pix,c]
__global__ __launch_bounds__(256) void k_scatter(const int* __restrict__ flat,
                                                 const float* __restrict__ depth,
                                                 const float* __restrict__ featT,
                                                 float* __restrict__ pooled) {
    unsigned idx = blockIdx.x*256u + threadIdx.x;   // NPTS*80
    unsigned p = idx / CIMG;
    unsigned c = idx % CIMG;
    int cell = flat[p];
    if (cell < 0) return;
    unsigned yx = p % PIX;
    unsigned n = p / (PIX*DD);
    float v = depth[p] * featT[(size_t)(n*PIX+yx)*CIMG + c];
    atomicAdd(pooled + (size_t)cell*CIMG + c, v);
}

// downsample convs on NHWC, weights pre-transposed to [tap, ci, co]
// STRIDE=2: in [360,360,80] -> out [180,180,80] (NHWC)
// STRIDE=1: in [180,180,80] -> out NCHW [80,180,180] (final output)
template<int STRIDE, int HIN, int HOUT, bool NCHW_OUT>
__global__ __launch_bounds__(320) void k_ds(const float* __restrict__ in,
                                            const float* __restrict__ tw,
                                            const float* __restrict__ s,
                                            const float* __restrict__ t,
                                            float* __restrict__ out) {
    int tid = threadIdx.x;            // 320 = 4 pixels x 80 co
    int j  = tid / CIMG;
    int co = tid % CIMG;
    int op = blockIdx.x*4 + j;        // HOUT*HOUT
    int xo = op / HOUT, yo = op % HOUT;
    float acc = 0.f;
    int xi0 = xo*STRIDE - 1, yi0 = yo*STRIDE - 1;
    #pragma unroll
    for (int kx=0;kx<3;kx++) {
        int xi = xi0+kx;
        if ((unsigned)xi >= HIN) continue;
        #pragma unroll
        for (int ky=0;ky<3;ky++) {
            int yi = yi0+ky;
            if ((unsigned)yi >= HIN) continue;
            const float* ip = in + (size_t)(xi*HIN + yi)*CIMG;
            const float* wp = tw + (size_t)((kx*3+ky)*CIMG)*CIMG + co;
            for (int ci=0; ci<CIMG; ci++)
                acc = fmaf(ip[ci], wp[(size_t)ci*CIMG], acc);
        }
    }
    float r = fmaxf(fmaf(acc, s[co], t[co]), 0.f);
    if (NCHW_OUT) out[((size_t)co*HOUT + xo)*HOUT + yo] = r;
    else          out[((size_t)xo*HOUT + yo)*CIMG + co] = r;
}

// ---------------- host launcher ----------------
extern "C" void kernel_launch(void* const* d_in, const int* in_sizes, int n_in,
                              void* d_out, int out_size, void* d_ws, size_t ws_size,
                              hipStream_t stream) {
    const float* x_img  = (const float*)d_in[0];
    const float* dimg   = (const float*)d_in[1];
    const float* c2l_R  = (const float*)d_in[2];
    const float* c2l_t  = (const float*)d_in[3];
    const float* intr   = (const float*)d_in[4];
    const float* prot   = (const float*)d_in[5];
    const float* ptran  = (const float*)d_in[6];
    const float* dt1_w  = (const float*)d_in[7];
    const float* dt1_b  = (const float*)d_in[8];
    const float* dt1_s  = (const float*)d_in[9];
    const float* dt1_t  = (const float*)d_in[10];
    const float* dt2_w  = (const float*)d_in[11];
    const float* dt2_b  = (const float*)d_in[12];
    const float* dt2_s  = (const float*)d_in[13];
    const float* dt2_t  = (const float*)d_in[14];
    const float* dt3_w  = (const float*)d_in[15];
    const float* dt3_b  = (const float*)d_in[16];
    const float* dt3_s  = (const float*)d_in[17];
    const float* dt3_t  = (const float*)d_in[18];
    const float* dn1_w  = (const float*)d_in[19];
    const float* dn1_b  = (const float*)d_in[20];
    const float* dn1_s  = (const float*)d_in[21];
    const float* dn1_t  = (const float*)d_in[22];
    const float* dn2_w  = (const float*)d_in[23];
    const float* dn2_b  = (const float*)d_in[24];
    const float* dn2_s  = (const float*)d_in[25];
    const float* dn2_t  = (const float*)d_in[26];
    const float* dn3_w  = (const float*)d_in[27];
    const float* dn3_b  = (const float*)d_in[28];
    const float* ds1_w  = (const float*)d_in[29];
    const float* ds1_s  = (const float*)d_in[30];
    const float* ds1_t  = (const float*)d_in[31];
    const float* ds2_w  = (const float*)d_in[32];
    const float* ds2_s  = (const float*)d_in[33];
    const float* ds2_t  = (const float*)d_in[34];

    float* ws = (float*)d_ws;
    float* mats   = ws + OFF_MATS;
    float* tw1    = ws + OFF_TW1;
    float* tw2    = ws + OFF_TW2;
    float* h1     = ws + OFF_A;     // [6,8,256,704]
    float* f2     = ws + OFF_A;     // [6,256,32,88]  (after h1 dead)
    float* pooled = ws + OFF_A;     // [360*360, 80]  (after f2 dead)
    float* h2     = ws + OFF_B;     // [6,32,64,176]
    float* f3     = ws + OFF_B;     // [6,139,32,88]  (after h2 dead)
    float* h3     = ws + OFF_C;     // [6,64,32,88]
    float* depth  = ws + OFF_C;     // [6,59,32,88]   (after h3 dead)
    float* f1     = ws + OFF_D;     // [6,256,32,88]
    float* featT  = ws + OFF_FEATT; // [6*2816, 80]   (after f1 dead)
    int*   flat   = (int*)(ws + OFF_FLAT);   // [996864]
    float* bev1   = ws + OFF_BEV1;  // [180*180, 80]
    float* outp   = (float*)d_out;  // [80,180,180]

    // prep
    k_cam_mats<<<1, 64, 0, stream>>>(prot, ptran, intr, c2l_R, c2l_t, mats);
    k_wtrans<<<225, 256, 0, stream>>>(ds1_w, tw1);
    k_wtrans<<<225, 256, 0, stream>>>(ds2_w, tw2);

    // dtransform
    k_dt1<<<4224, 256, 0, stream>>>(dimg, dt1_w, dt1_b, dt1_s, dt1_t, h1);
    k_dt2<<<dim3(44,32,NCAM), 256, 0, stream>>>(h1, dt2_w, dt2_b, dt2_s, dt2_t, h2);
    k_dt3<<<dim3(11,64,NCAM), 256, 0, stream>>>(h2, dt3_w, dt3_b, dt3_s, dt3_t, h3);

    // depthnet
    k_conv3x3<64,256,256><<<dim3(11,64,NCAM), 256, 0, stream>>>(h3, x_img, dn1_w, dn1_b, dn1_s, dn1_t, f1);
    k_conv3x3<256,0,256><<<dim3(11,64,NCAM), 256, 0, stream>>>(f1, f1, dn2_w, dn2_b, dn2_s, dn2_t, f2);
    k_dn3<<<dim3(11,35,NCAM), 256, 0, stream>>>(f2, dn3_w, dn3_b, f3);

    // softmax + feature transpose
    k_softmax_feat<<<66, 256, 0, stream>>>(f3, depth, featT);

    // geometry + bev_pool
    hipMemsetAsync(pooled, 0, (size_t)NXv*NXv*CIMG*sizeof(float), stream);
    k_voxel<<<3894, 256, 0, stream>>>(mats, flat);
    k_scatter<<<311520, 256, 0, stream>>>(flat, depth, featT, pooled);

    // downsample
    k_ds<2,360,180,false><<<8100, 320, 0, stream>>>(pooled, tw1, ds1_s, ds1_t, bev1);
    k_ds<1,180,180,true><<<8100, 320, 0, stream>>>(bev1, tw2, ds2_s, ds2_t, outp);
}

// Round 2
// 3340.064 us; speedup vs baseline: 1.0399x; 1.0399x over previous
//
#include <hip/hip_runtime.h>
#include <math.h>

// ---------------- problem constants ----------------
#define NCAM 6
#define IH 256
#define IW 704
#define FH 32
#define FW 88
#define DD 59
#define CIMG 80
#define NXv 360
#define PIX (FH*FW)           // 2816
#define IMGPIX (IH*IW)        // 180224
#define NPTS (NCAM*DD*PIX)    // 996864

// ---------------- ws arena offsets (in floats) ----------------
// persistent
#define OFF_MATS 0                      // 144
#define OFF_TW1  144                    // 57600
#define OFF_TW2  57744                  // 57600
// SEG_A: h1 (8,650,752) -> f2 (4,325,376) -> pooled (10,368,000)
#define OFF_A    115344
// transposed dn weights live in SEG_A after h1 is dead (after dt2),
// above f2 (4,325,376), dead before pooled memset.
#define OFF_TWD1 (OFF_A + 4325376)      // 737,280  [320*9*256]
#define OFF_TWD2 (OFF_TWD1 + 737280)    // 589,824  [256*9*256]
#define OFF_TWD3 (OFF_TWD2 + 589824)    // 36,864   [256*144]
// SEG_B: h2 (2,162,688) -> f3 (2,348,544)
#define OFF_B    10483344
// SEG_C: h3 (1,081,344) -> depth (996,864)
#define OFF_C    12831888
// SEG_D: f1 (4,325,376) -> featT (1,351,680) + flat (996,864) + bev1 (2,592,000)
#define OFF_D      13913232
#define OFF_FEATT  OFF_D
#define OFF_FLAT   (OFF_D + 1351680)
#define OFF_BEV1   (OFF_D + 2348544)
// total: 18,853,776 floats = ~75.4 MB (unchanged from R0)

// ---------------- small helpers ----------------
__device__ __forceinline__ void inv3(const float* m, float* o) {
    float a=m[0],b=m[1],c=m[2],d=m[3],e=m[4],f=m[5],g=m[6],h=m[7],i=m[8];
    float A =  (e*i - f*h);
    float B = -(d*i - f*g);
    float C =  (d*h - e*g);
    float det = a*A + b*B + c*C;
    float r = 1.f/det;
    o[0]=A*r;            o[1]=-(b*i - c*h)*r; o[2]=(b*f - c*e)*r;
    o[3]=B*r;            o[4]=(a*i - c*g)*r;  o[5]=-(a*f - c*d)*r;
    o[6]=C*r;            o[7]=-(a*h - b*g)*r; o[8]=(a*e - b*d)*r;
}

__global__ void k_cam_mats(const float* __restrict__ prot, const float* __restrict__ ptran,
                           const float* __restrict__ intr, const float* __restrict__ Rcl,
                           const float* __restrict__ tcl, float* __restrict__ mats) {
    int n = threadIdx.x;
    if (n >= NCAM) return;
    float P[9], Km[9], R[9], A[9], Ki[9];
    for (int i=0;i<9;i++){ P[i]=prot[n*9+i]; Km[i]=intr[n*9+i]; R[i]=Rcl[n*9+i]; }
    inv3(P, A); inv3(Km, Ki);
    float* M = mats + n*24;
    for (int i=0;i<9;i++) M[i] = A[i];
    for (int r=0;r<3;r++)
        M[9+r] = -(A[r*3+0]*ptran[n*3+0] + A[r*3+1]*ptran[n*3+1] + A[r*3+2]*ptran[n*3+2]);
    for (int r=0;r<3;r++) for (int c=0;c<3;c++)
        M[12 + r*3+c] = R[r*3+0]*Ki[0*3+c] + R[r*3+1]*Ki[1*3+c] + R[r*3+2]*Ki[2*3+c];
    for (int r=0;r<3;r++) M[21+r] = tcl[n*3+r];
}

// transpose [80,80,3,3] -> [3,3,80(ci),80(co)]
__global__ void k_wtrans(const float* __restrict__ w, float* __restrict__ tw) {
    int i = blockIdx.x*blockDim.x + threadIdx.x;
    if (i >= CIMG*CIMG*9) return;
    int kw = i % 3; int r = i/3;
    int kh = r % 3; r /= 3;
    int ci = r % CIMG; int co = r / CIMG;
    tw[((kh*3+kw)*CIMG + ci)*CIMG + co] = w[i];
}

// transpose conv weight [COUT][CIN][3][3] -> [CIN][9][COUT]
template<int CIN, int COUT>
__global__ void k_wtrans_dn(const float* __restrict__ w, float* __restrict__ tw) {
    int i = blockIdx.x*blockDim.x + threadIdx.x;
    if (i >= COUT*CIN*9) return;
    int co = i / (CIN*9);
    int r = i % (CIN*9);
    int ci = r / 9;
    int k = r % 9;
    tw[((size_t)ci*9 + k)*COUT + co] = w[i];
}

// transpose dn3 weight [139][256] -> [256][144] (co padded to 144 with 0)
__global__ void k_wtrans_dn3(const float* __restrict__ w, float* __restrict__ tw) {
    int i = blockIdx.x*blockDim.x + threadIdx.x;   // 256*144
    if (i >= 256*144) return;
    int ci = i / 144, co = i % 144;
    tw[i] = (co < 139) ? w[co*256 + ci] : 0.f;
}

// dtransform conv1: 1x1, 1->8, + bias, BN, ReLU
__global__ __launch_bounds__(256) void k_dt1(const float* __restrict__ d, const float* __restrict__ w,
                                             const float* __restrict__ b, const float* __restrict__ s,
                                             const float* __restrict__ t, float* __restrict__ out) {
    int i = blockIdx.x*256 + threadIdx.x;
    if (i >= NCAM*IMGPIX) return;
    int n = i / IMGPIX;
    int yx = i % IMGPIX;
    float v = d[i];
    #pragma unroll
    for (int c=0;c<8;c++) {
        float r = fmaxf(fmaf(fmaf(v, w[c], b[c]), s[c], t[c]), 0.f);
        out[(size_t)(n*8+c)*IMGPIX + yx] = r;
    }
}

// dtransform conv2: 5x5 s4 p2, 8->32, 4 co per thread
__global__ __launch_bounds__(256) void k_dt2(const float* __restrict__ in, const float* __restrict__ w,
                                             const float* __restrict__ b, const float* __restrict__ s,
                                             const float* __restrict__ t, float* __restrict__ out) {
    const int co0 = blockIdx.y*4, n = blockIdx.z;
    int o = blockIdx.x*256 + threadIdx.x;      // 64*176 = 11264
    int yo = o / 176, xo = o % 176;
    float acc[4];
    #pragma unroll
    for (int j=0;j<4;j++) acc[j] = b[co0+j];
    int yi0 = yo*4-2, xi0 = xo*4-2;
    for (int ci=0; ci<8; ci++) {
        const float* ip = in + (size_t)(n*8+ci)*IMGPIX;
        float v[25];
        #pragma unroll
        for (int ky=0;ky<5;ky++) {
            int yi = yi0+ky;
            bool yv = ((unsigned)yi < IH);
            #pragma unroll
            for (int kx=0;kx<5;kx++) {
                int xi = xi0+kx;
                v[ky*5+kx] = (yv && ((unsigned)xi < IW)) ? ip[yi*IW+xi] : 0.f;
            }
        }
        #pragma unroll
        for (int j=0;j<4;j++) {
            const float* wp = w + (co0+j)*200 + ci*25;
            #pragma unroll
            for (int k=0;k<25;k++) acc[j] = fmaf(v[k], wp[k], acc[j]);
        }
    }
    #pragma unroll
    for (int j=0;j<4;j++)
        out[((size_t)(n*32+co0+j)*64+yo)*176+xo] = fmaxf(fmaf(acc[j], s[co0+j], t[co0+j]), 0.f);
}

// dtransform conv3: 5x5 s2 p2, 32->64, 4 co per thread
__global__ __launch_bounds__(256) void k_dt3(const float* __restrict__ in, const float* __restrict__ w,
                                             const float* __restrict__ b, const float* __restrict__ s,
                                             const float* __restrict__ t, float* __restrict__ out) {
    const int co0 = blockIdx.y*4, n = blockIdx.z;
    int o = blockIdx.x*256 + threadIdx.x;      // 2816
    int yo = o / FW, xo = o % FW;
    float acc[4];
    #pragma unroll
    for (int j=0;j<4;j++) acc[j] = b[co0+j];
    int yi0 = yo*2-2, xi0 = xo*2-2;
    for (int ci=0; ci<32; ci++) {
        const float* ip = in + (size_t)(n*32+ci)*(64*176);
        float v[25];
        #pragma unroll
        for (int ky=0;ky<5;ky++) {
            int yi = yi0+ky;
            bool yv = ((unsigned)yi < 64);
            #pragma unroll
            for (int kx=0;kx<5;kx++) {
                int xi = xi0+kx;
                v[ky*5+kx] = (yv && ((unsigned)xi < 176)) ? ip[yi*176+xi] : 0.f;
            }
        }
        #pragma unroll
        for (int j=0;j<4;j++) {
            const float* wp = w + (co0+j)*800 + ci*25;
            #pragma unroll
            for (int k=0;k<25;k++) acc[j] = fmaf(v[k], wp[k], acc[j]);
        }
    }
    #pragma unroll
    for (int j=0;j<4;j++)
        out[((size_t)(n*64+co0+j)*FH+yo)*FW+xo] = fmaxf(fmaf(acc[j], s[co0+j], t[co0+j]), 0.f);
}

// 3x3 pad1 conv on 32x88, register-blocked: 8 co x 2 px per thread,
// weights pre-transposed to [ci][9][COUT] (wave-uniform float4 loads).
template<int C1, int C2, int COUT>
__global__ __launch_bounds__(128) void k_conv3x3_v2(const float* __restrict__ src1,
                                                    const float* __restrict__ src2,
                                                    const float* __restrict__ tw,
                                                    const float* __restrict__ b,
                                                    const float* __restrict__ s,
                                                    const float* __restrict__ t,
                                                    float* __restrict__ out) {
    const int n = blockIdx.z;
    const int co0 = blockIdx.y*8;
    int gid = blockIdx.x*128 + threadIdx.x;     // 0..1407 (pixel pairs)
    int y = gid / 44;
    int x0 = (gid % 44) * 2;
    bool xm1 = (x0 > 0);
    bool xp2 = (x0 < 86);

    float a0[8], a1[8];
    #pragma unroll
    for (int j=0;j<8;j++) { a0[j] = b[co0+j]; a1[j] = b[co0+j]; }

    #pragma unroll 1
    for (int half=0; half<2; half++) {
        const int CC = half ? C2 : C1;
        if (CC == 0) continue;
        const float* src = half ? src2 : src1;
        const int ci_base = half ? C1 : 0;
        for (int ci=0; ci<CC; ci++) {
            const float* ip = src + (size_t)(n*CC+ci)*PIX;
            float tp[3][4];
            #pragma unroll
            for (int r=0;r<3;r++) {
                int yy = y-1+r;
                bool rv = ((unsigned)yy < FH);
                const float* rp = ip + yy*FW + x0;
                tp[r][0] = (rv && xm1) ? rp[-1] : 0.f;
                tp[r][1] = rv ? rp[0] : 0.f;
                tp[r][2] = rv ? rp[1] : 0.f;
                tp[r][3] = (rv && xp2) ? rp[2] : 0.f;
            }
            const float4* wq = (const float4*)(tw + (size_t)(ci_base+ci)*9*COUT + co0);
            #pragma unroll
            for (int r=0;r<3;r++) {
                #pragma unroll
                for (int c=0;c<3;c++) {
                    int k = r*3+c;
                    float4 wa = wq[k*(COUT/4)];
                    float4 wb = wq[k*(COUT/4)+1];
                    float ta = tp[r][c], tb = tp[r][c+1];
                    a0[0]=fmaf(ta,wa.x,a0[0]); a1[0]=fmaf(tb,wa.x,a1[0]);
                    a0[1]=fmaf(ta,wa.y,a0[1]); a1[1]=fmaf(tb,wa.y,a1[1]);
                    a0[2]=fmaf(ta,wa.z,a0[2]); a1[2]=fmaf(tb,wa.z,a1[2]);
                    a0[3]=fmaf(ta,wa.w,a0[3]); a1[3]=fmaf(tb,wa.w,a1[3]);
                    a0[4]=fmaf(ta,wb.x,a0[4]); a1[4]=fmaf(tb,wb.x,a1[4]);
                    a0[5]=fmaf(ta,wb.y,a0[5]); a1[5]=fmaf(tb,wb.y,a1[5]);
                    a0[6]=fmaf(ta,wb.z,a0[6]); a1[6]=fmaf(tb,wb.z,a1[6]);
                    a0[7]=fmaf(ta,wb.w,a0[7]); a1[7]=fmaf(tb,wb.w,a1[7]);
                }
            }
        }
    }
    int o = y*FW + x0;
    #pragma unroll
    for (int j=0;j<8;j++) {
        float* op = out + ((size_t)n*COUT + co0+j)*PIX + o;
        op[0] = fmaxf(fmaf(a0[j], s[co0+j], t[co0+j]), 0.f);
        op[1] = fmaxf(fmaf(a1[j], s[co0+j], t[co0+j]), 0.f);
    }
}

// dn3: 1x1 conv 256->139 + bias, 8 co per thread, weights [ci][144co]
__global__ __launch_bounds__(256) void k_dn3_v2(const float* __restrict__ in,
                                                const float* __restrict__ tw,
                                                const float* __restrict__ b,
                                                float* __restrict__ out) {
    int o = blockIdx.x*256 + threadIdx.x;       // 2816
    int n = blockIdx.z;
    int co0 = blockIdx.y*8;                      // 18 groups (144)
    const float* ip = in + (size_t)n*256*PIX + o;
    float acc[8];
    #pragma unroll
    for (int j=0;j<8;j++) acc[j]=0.f;
    for (int ci=0; ci<256; ci++) {
        float v = ip[(size_t)ci*PIX];
        const float4* wq = (const float4*)(tw + ci*144 + co0);
        float4 wa = wq[0], wb = wq[1];
        acc[0]=fmaf(v,wa.x,acc[0]); acc[1]=fmaf(v,wa.y,acc[1]);
        acc[2]=fmaf(v,wa.z,acc[2]); acc[3]=fmaf(v,wa.w,acc[3]);
        acc[4]=fmaf(v,wb.x,acc[4]); acc[5]=fmaf(v,wb.y,acc[5]);
        acc[6]=fmaf(v,wb.z,acc[6]); acc[7]=fmaf(v,wb.w,acc[7]);
    }
    #pragma unroll
    for (int j=0;j<8;j++) {
        int co = co0+j;
        if (co < 139) out[((size_t)n*139+co)*PIX + o] = acc[j] + b[co];
    }
}

// softmax over first 59 channels -> depth; copy 80 img feats -> featT [n*PIX, 80]
__global__ __launch_bounds__(256) void k_softmax_feat(const float* __restrict__ f3,
                                                      float* __restrict__ depth,
                                                      float* __restrict__ featT) {
    int o = blockIdx.x*256 + threadIdx.x;       // 16896
    int n = o / PIX, yx = o % PIX;
    const float* fp = f3 + (size_t)n*139*PIX + yx;
    float m = -1e30f;
    for (int d=0; d<DD; d++) m = fmaxf(m, fp[(size_t)d*PIX]);
    float sum = 0.f;
    for (int d=0; d<DD; d++) sum += expf(fp[(size_t)d*PIX]-m);
    float inv = 1.f/sum;
    for (int d=0; d<DD; d++)
        depth[((size_t)n*DD+d)*PIX + yx] = expf(fp[(size_t)d*PIX]-m)*inv;
    float* ft = featT + (size_t)o*CIMG;
    for (int c=0; c<CIMG; c++) ft[c] = fp[(size_t)(DD+c)*PIX];
}

// frustum -> lidar -> voxel index (or -1)
__global__ __launch_bounds__(256) void k_voxel(const float* __restrict__ mats, int* __restrict__ flat) {
    int p = blockIdx.x*256 + threadIdx.x;
    if (p >= NPTS) return;
    int x = p % FW; int t1 = p / FW;
    int y = t1 % FH; int t2 = t1 / FH;
    int dd = t2 % DD; int n = t2 / DD;
    float xf = x * (703.f/87.f);
    float yf = y * (255.f/31.f);
    float df = 1.f + (float)dd;
    const float* M = mats + n*24;
    float qx = M[0]*xf + M[1]*yf + M[2]*df + M[9];
    float qy = M[3]*xf + M[4]*yf + M[5]*df + M[10];
    float qz = M[6]*xf + M[7]*yf + M[8]*df + M[11];
    float rx = qx*qz, ry = qy*qz, rz = qz;
    float wx = M[12]*rx + M[13]*ry + M[14]*rz + M[21];
    float wy = M[15]*rx + M[16]*ry + M[17]*rz + M[22];
    float wz = M[18]*rx + M[19]*ry + M[20]*rz + M[23];
    int gx = (int)((wx + 54.f) / 0.3f);
    int gy = (int)((wy + 54.f) / 0.3f);
    int gz = (int)((wz + 10.f) / 20.f);
    bool kept = ((unsigned)gx < NXv) && ((unsigned)gy < NXv) && (gz == 0);
    flat[p] = kept ? (gx*NXv + gy) : -1;
}

// scatter: pooled[cell,c..c+3] += depth[p] * featT[pix,c..c+3], 4 channels/thread
__global__ __launch_bounds__(256) void k_scatter(const int* __restrict__ flat,
                                                 const float* __restrict__ depth,
                                                 const float* __restrict__ featT,
                                                 float* __restrict__ pooled) {
    unsigned idx = blockIdx.x*256u + threadIdx.x;   // NPTS*20
    unsigned p = idx / 20u;
    unsigned q = idx % 20u;
    int cell = flat[p];
    if (cell < 0) return;
    unsigned yx = p % PIX;
    unsigned n = p / (PIX*DD);
    float dv = depth[p];
    float4 f = *(const float4*)(featT + (size_t)(n*PIX+yx)*CIMG + q*4);
    float* dst = pooled + (size_t)cell*CIMG + q*4;
    atomicAdd(dst+0, dv*f.x);
    atomicAdd(dst+1, dv*f.y);
    atomicAdd(dst+2, dv*f.z);
    atomicAdd(dst+3, dv*f.w);
}

// downsample convs on NHWC, weights pre-transposed to [tap, ci, co]
template<int STRIDE, int HIN, int HOUT, bool NCHW_OUT>
__global__ __launch_bounds__(320) void k_ds(const float* __restrict__ in,
                                            const float* __restrict__ tw,
                                            const float* __restrict__ s,
                                            const float* __restrict__ t,
                                            float* __restrict__ out) {
    int tid = threadIdx.x;            // 320 = 4 pixels x 80 co
    int j  = tid / CIMG;
    int co = tid % CIMG;
    int op = blockIdx.x*4 + j;        // HOUT*HOUT
    int xo = op / HOUT, yo = op % HOUT;
    float acc = 0.f;
    int xi0 = xo*STRIDE - 1, yi0 = yo*STRIDE - 1;
    #pragma unroll
    for (int kx=0;kx<3;kx++) {
        int xi = xi0+kx;
        if ((unsigned)xi >= HIN) continue;
        #pragma unroll
        for (int ky=0;ky<3;ky++) {
            int yi = yi0+ky;
            if ((unsigned)yi >= HIN) continue;
            const float* ip = in + (size_t)(xi*HIN + yi)*CIMG;
            const float* wp = tw + (size_t)((kx*3+ky)*CIMG)*CIMG + co;
            for (int ci=0; ci<CIMG; ci++)
                acc = fmaf(ip[ci], wp[(size_t)ci*CIMG], acc);
        }
    }
    float r = fmaxf(fmaf(acc, s[co], t[co]), 0.f);
    if (NCHW_OUT) out[((size_t)co*HOUT + xo)*HOUT + yo] = r;
    else          out[((size_t)xo*HOUT + yo)*CIMG + co] = r;
}

// ---------------- host launcher ----------------
extern "C" void kernel_launch(void* const* d_in, const int* in_sizes, int n_in,
                              void* d_out, int out_size, void* d_ws, size_t ws_size,
                              hipStream_t stream) {
    const float* x_img  = (const float*)d_in[0];
    const float* dimg   = (const float*)d_in[1];
    const float* c2l_R  = (const float*)d_in[2];
    const float* c2l_t  = (const float*)d_in[3];
    const float* intr   = (const float*)d_in[4];
    const float* prot   = (const float*)d_in[5];
    const float* ptran  = (const float*)d_in[6];
    const float* dt1_w  = (const float*)d_in[7];
    const float* dt1_b  = (const float*)d_in[8];
    const float* dt1_s  = (const float*)d_in[9];
    const float* dt1_t  = (const float*)d_in[10];
    const float* dt2_w  = (const float*)d_in[11];
    const float* dt2_b  = (const float*)d_in[12];
    const float* dt2_s  = (const float*)d_in[13];
    const float* dt2_t  = (const float*)d_in[14];
    const float* dt3_w  = (const float*)d_in[15];
    const float* dt3_b  = (const float*)d_in[16];
    const float* dt3_s  = (const float*)d_in[17];
    const float* dt3_t  = (const float*)d_in[18];
    const float* dn1_w  = (const float*)d_in[19];
    const float* dn1_b  = (const float*)d_in[20];
    const float* dn1_s  = (const float*)d_in[21];
    const float* dn1_t  = (const float*)d_in[22];
    const float* dn2_w  = (const float*)d_in[23];
    const float* dn2_b  = (const float*)d_in[24];
    const float* dn2_s  = (const float*)d_in[25];
    const float* dn2_t  = (const float*)d_in[26];
    const float* dn3_w  = (const float*)d_in[27];
    const float* dn3_b  = (const float*)d_in[28];
    const float* ds1_w  = (const float*)d_in[29];
    const float* ds1_s  = (const float*)d_in[30];
    const float* ds1_t  = (const float*)d_in[31];
    const float* ds2_w  = (const float*)d_in[32];
    const float* ds2_s  = (const float*)d_in[33];
    const float* ds2_t  = (const float*)d_in[34];

    float* ws = (float*)d_ws;
    float* mats   = ws + OFF_MATS;
    float* tw1    = ws + OFF_TW1;
    float* tw2    = ws + OFF_TW2;
    float* h1     = ws + OFF_A;     // [6,8,256,704]
    float* f2     = ws + OFF_A;     // [6,256,32,88]
    float* pooled = ws + OFF_A;     // [360*360, 80]
    float* twd1   = ws + OFF_TWD1;  // [320,9,256]
    float* twd2   = ws + OFF_TWD2;  // [256,9,256]
    float* twd3   = ws + OFF_TWD3;  // [256,144]
    float* h2     = ws + OFF_B;     // [6,32,64,176]
    float* f3     = ws + OFF_B;     // [6,139,32,88]
    float* h3     = ws + OFF_C;     // [6,64,32,88]
    float* depth  = ws + OFF_C;     // [6,59,32,88]
    float* f1     = ws + OFF_D;     // [6,256,32,88]
    float* featT  = ws + OFF_FEATT; // [6*2816, 80]
    int*   flat   = (int*)(ws + OFF_FLAT);
    float* bev1   = ws + OFF_BEV1;  // [180*180, 80]
    float* outp   = (float*)d_out;  // [80,180,180]

    // prep (ds weight transposes; dn transposes must wait until h1 is dead)
    k_cam_mats<<<1, 64, 0, stream>>>(prot, ptran, intr, c2l_R, c2l_t, mats);
    k_wtrans<<<225, 256, 0, stream>>>(ds1_w, tw1);
    k_wtrans<<<225, 256, 0, stream>>>(ds2_w, tw2);

    // dtransform
    k_dt1<<<4224, 256, 0, stream>>>(dimg, dt1_w, dt1_b, dt1_s, dt1_t, h1);
    k_dt2<<<dim3(44,8,NCAM), 256, 0, stream>>>(h1, dt2_w, dt2_b, dt2_s, dt2_t, h2);

    // h1 dead now -> transpose dn weights into its upper region
    k_wtrans_dn<320,256><<<2880, 256, 0, stream>>>(dn1_w, twd1);
    k_wtrans_dn<256,256><<<2304, 256, 0, stream>>>(dn2_w, twd2);
    k_wtrans_dn3<<<144, 256, 0, stream>>>(dn3_w, twd3);

    k_dt3<<<dim3(11,16,NCAM), 256, 0, stream>>>(h2, dt3_w, dt3_b, dt3_s, dt3_t, h3);

    // depthnet (register-blocked, transposed weights)
    k_conv3x3_v2<64,256,256><<<dim3(11,32,NCAM), 128, 0, stream>>>(h3, x_img, twd1, dn1_b, dn1_s, dn1_t, f1);
    k_conv3x3_v2<256,0,256><<<dim3(11,32,NCAM), 128, 0, stream>>>(f1, f1, twd2, dn2_b, dn2_s, dn2_t, f2);
    k_dn3_v2<<<dim3(11,18,NCAM), 256, 0, stream>>>(f2, twd3, dn3_b, f3);

    // softmax + feature transpose
    k_softmax_feat<<<66, 256, 0, stream>>>(f3, depth, featT);

    // geometry + bev_pool
    hipMemsetAsync(pooled, 0, (size_t)NXv*NXv*CIMG*sizeof(float), stream);
    k_voxel<<<3894, 256, 0, stream>>>(mats, flat);
    k_scatter<<<77880, 256, 0, stream>>>(flat, depth, featT, pooled);

    // downsample
    k_ds<2,360,180,false><<<8100, 320, 0, stream>>>(pooled, tw1, ds1_s, ds1_t, bev1);
    k_ds<1,180,180,true><<<8100, 320, 0, stream>>>(bev1, tw2, ds2_s, ds2_t, outp);
}

// Round 3
// 2703.706 us; speedup vs baseline: 1.2847x; 1.2354x over previous
//
#include <hip/hip_runtime.h>
#include <math.h>

// ---------------- problem constants ----------------
#define NCAM 6
#define IH 256
#define IW 704
#define FH 32
#define FW 88
#define DD 59
#define CIMG 80
#define NXv 360
#define PIX (FH*FW)           // 2816
#define IMGPIX (IH*IW)        // 180224
#define NPTS (NCAM*DD*PIX)    // 996864
#define NCELLS (NXv*NXv)      // 129600
#define NB 127                // scan blocks: ceil(129600/1024)

// ---------------- ws arena offsets (in floats) ----------------
// persistent
#define OFF_MATS 0                      // 144
#define OFF_TW1  144                    // 57600
#define OFF_TW2  57744                  // 57600
// SEG_A: h1 (8,650,752) -> f2 (4,325,376) -> pooled (10,368,000)
#define OFF_A    115344
// transposed dn weights in SEG_A above f2, alive only between dt2 and dn3
#define OFF_TWD1 (OFF_A + 4325376)      // 737,280  [320*9*256]
#define OFF_TWD2 (OFF_TWD1 + 737280)    // 589,824  [256*9*256]
#define OFF_TWD3 (OFF_TWD2 + 589824)    // 36,864   [256*144]
// SEG_B: h2 (2,162,688) -> f3 (2,348,544) -> bev_pool sort scratch
#define OFF_B    10483344
#define OFF_CNT    (OFF_B)              // 129,600 ints
#define OFF_INCL   (OFF_B + 131072)     // 129,600 ints
#define OFF_OFFS   (OFF_B + 262144)     // 129,600 ints
#define OFF_CURSOR (OFF_B + 393216)     // 129,600 ints
#define OFF_BSUM   (OFF_B + 524288)     // 128 ints
#define OFF_BSX    (OFF_B + 524544)     // 128 ints
#define OFF_ORDER  (OFF_B + 525312)     // 996,864 ints  (ends +1,522,176 < 2,348,544)
// SEG_C: h3 (1,081,344) -> depth (996,864)
#define OFF_C    12831888
// SEG_D: f1 (4,325,376) -> featT (1,351,680) + flat (996,864) + bev1 (2,592,000)
#define OFF_D      13913232
#define OFF_FEATT  OFF_D
#define OFF_FLAT   (OFF_D + 1351680)
#define OFF_BEV1   (OFF_D + 2348544)
// total: 18,853,776 floats = ~75.4 MB (unchanged)

// ---------------- small helpers ----------------
__device__ __forceinline__ void inv3(const float* m, float* o) {
    float a=m[0],b=m[1],c=m[2],d=m[3],e=m[4],f=m[5],g=m[6],h=m[7],i=m[8];
    float A =  (e*i - f*h);
    float B = -(d*i - f*g);
    float C =  (d*h - e*g);
    float det = a*A + b*B + c*C;
    float r = 1.f/det;
    o[0]=A*r;            o[1]=-(b*i - c*h)*r; o[2]=(b*f - c*e)*r;
    o[3]=B*r;            o[4]=(a*i - c*g)*r;  o[5]=-(a*f - c*d)*r;
    o[6]=C*r;            o[7]=-(a*h - b*g)*r; o[8]=(a*e - b*d)*r;
}

__global__ void k_cam_mats(const float* __restrict__ prot, const float* __restrict__ ptran,
                           const float* __restrict__ intr, const float* __restrict__ Rcl,
                           const float* __restrict__ tcl, float* __restrict__ mats) {
    int n = threadIdx.x;
    if (n >= NCAM) return;
    float P[9], Km[9], R[9], A[9], Ki[9];
    for (int i=0;i<9;i++){ P[i]=prot[n*9+i]; Km[i]=intr[n*9+i]; R[i]=Rcl[n*9+i]; }
    inv3(P, A); inv3(Km, Ki);
    float* M = mats + n*24;
    for (int i=0;i<9;i++) M[i] = A[i];
    for (int r=0;r<3;r++)
        M[9+r] = -(A[r*3+0]*ptran[n*3+0] + A[r*3+1]*ptran[n*3+1] + A[r*3+2]*ptran[n*3+2]);
    for (int r=0;r<3;r++) for (int c=0;c<3;c++)
        M[12 + r*3+c] = R[r*3+0]*Ki[0*3+c] + R[r*3+1]*Ki[1*3+c] + R[r*3+2]*Ki[2*3+c];
    for (int r=0;r<3;r++) M[21+r] = tcl[n*3+r];
}

// transpose [80,80,3,3] -> [3,3,80(ci),80(co)]
__global__ void k_wtrans(const float* __restrict__ w, float* __restrict__ tw) {
    int i = blockIdx.x*blockDim.x + threadIdx.x;
    if (i >= CIMG*CIMG*9) return;
    int kw = i % 3; int r = i/3;
    int kh = r % 3; r /= 3;
    int ci = r % CIMG; int co = r / CIMG;
    tw[((kh*3+kw)*CIMG + ci)*CIMG + co] = w[i];
}

// transpose conv weight [COUT][CIN][3][3] -> [CIN][9][COUT]
template<int CIN, int COUT>
__global__ void k_wtrans_dn(const float* __restrict__ w, float* __restrict__ tw) {
    int i = blockIdx.x*blockDim.x + threadIdx.x;
    if (i >= COUT*CIN*9) return;
    int co = i / (CIN*9);
    int r = i % (CIN*9);
    int ci = r / 9;
    int k = r % 9;
    tw[((size_t)ci*9 + k)*COUT + co] = w[i];
}

// transpose dn3 weight [139][256] -> [256][144] (co padded to 144 with 0)
__global__ void k_wtrans_dn3(const float* __restrict__ w, float* __restrict__ tw) {
    int i = blockIdx.x*blockDim.x + threadIdx.x;   // 256*144
    if (i >= 256*144) return;
    int ci = i / 144, co = i % 144;
    tw[i] = (co < 139) ? w[co*256 + ci] : 0.f;
}

// dtransform conv1: 1x1, 1->8, + bias, BN, ReLU
__global__ __launch_bounds__(256) void k_dt1(const float* __restrict__ d, const float* __restrict__ w,
                                             const float* __restrict__ b, const float* __restrict__ s,
                                             const float* __restrict__ t, float* __restrict__ out) {
    int i = blockIdx.x*256 + threadIdx.x;
    if (i >= NCAM*IMGPIX) return;
    int n = i / IMGPIX;
    int yx = i % IMGPIX;
    float v = d[i];
    #pragma unroll
    for (int c=0;c<8;c++) {
        float r = fmaxf(fmaf(fmaf(v, w[c], b[c]), s[c], t[c]), 0.f);
        out[(size_t)(n*8+c)*IMGPIX + yx] = r;
    }
}

// dtransform conv2: 5x5 s4 p2, 8->32, 4 co per thread
__global__ __launch_bounds__(256) void k_dt2(const float* __restrict__ in, const float* __restrict__ w,
                                             const float* __restrict__ b, const float* __restrict__ s,
                                             const float* __restrict__ t, float* __restrict__ out) {
    const int co0 = blockIdx.y*4, n = blockIdx.z;
    int o = blockIdx.x*256 + threadIdx.x;      // 64*176 = 11264
    int yo = o / 176, xo = o % 176;
    float acc[4];
    #pragma unroll
    for (int j=0;j<4;j++) acc[j] = b[co0+j];
    int yi0 = yo*4-2, xi0 = xo*4-2;
    for (int ci=0; ci<8; ci++) {
        const float* ip = in + (size_t)(n*8+ci)*IMGPIX;
        float v[25];
        #pragma unroll
        for (int ky=0;ky<5;ky++) {
            int yi = yi0+ky;
            bool yv = ((unsigned)yi < IH);
            #pragma unroll
            for (int kx=0;kx<5;kx++) {
                int xi = xi0+kx;
                v[ky*5+kx] = (yv && ((unsigned)xi < IW)) ? ip[yi*IW+xi] : 0.f;
            }
        }
        #pragma unroll
        for (int j=0;j<4;j++) {
            const float* wp = w + (co0+j)*200 + ci*25;
            #pragma unroll
            for (int k=0;k<25;k++) acc[j] = fmaf(v[k], wp[k], acc[j]);
        }
    }
    #pragma unroll
    for (int j=0;j<4;j++)
        out[((size_t)(n*32+co0+j)*64+yo)*176+xo] = fmaxf(fmaf(acc[j], s[co0+j], t[co0+j]), 0.f);
}

// dtransform conv3: 5x5 s2 p2, 32->64, 4 co per thread
__global__ __launch_bounds__(256) void k_dt3(const float* __restrict__ in, const float* __restrict__ w,
                                             const float* __restrict__ b, const float* __restrict__ s,
                                             const float* __restrict__ t, float* __restrict__ out) {
    const int co0 = blockIdx.y*4, n = blockIdx.z;
    int o = blockIdx.x*256 + threadIdx.x;      // 2816
    int yo = o / FW, xo = o % FW;
    float acc[4];
    #pragma unroll
    for (int j=0;j<4;j++) acc[j] = b[co0+j];
    int yi0 = yo*2-2, xi0 = xo*2-2;
    for (int ci=0; ci<32; ci++) {
        const float* ip = in + (size_t)(n*32+ci)*(64*176);
        float v[25];
        #pragma unroll
        for (int ky=0;ky<5;ky++) {
            int yi = yi0+ky;
            bool yv = ((unsigned)yi < 64);
            #pragma unroll
            for (int kx=0;kx<5;kx++) {
                int xi = xi0+kx;
                v[ky*5+kx] = (yv && ((unsigned)xi < 176)) ? ip[yi*176+xi] : 0.f;
            }
        }
        #pragma unroll
        for (int j=0;j<4;j++) {
            const float* wp = w + (co0+j)*800 + ci*25;
            #pragma unroll
            for (int k=0;k<25;k++) acc[j] = fmaf(v[k], wp[k], acc[j]);
        }
    }
    #pragma unroll
    for (int j=0;j<4;j++)
        out[((size_t)(n*64+co0+j)*FH+yo)*FW+xo] = fmaxf(fmaf(acc[j], s[co0+j], t[co0+j]), 0.f);
}

// 3x3 pad1 conv on 32x88, register-blocked: 8 co x 2 px per thread,
// weights pre-transposed to [ci][9][COUT] (wave-uniform float4 loads).
template<int C1, int C2, int COUT>
__global__ __launch_bounds__(128) void k_conv3x3_v2(const float* __restrict__ src1,
                                                    const float* __restrict__ src2,
                                                    const float* __restrict__ tw,
                                                    const float* __restrict__ b,
                                                    const float* __restrict__ s,
                                                    const float* __restrict__ t,
                                                    float* __restrict__ out) {
    const int n = blockIdx.z;
    const int co0 = blockIdx.y*8;
    int gid = blockIdx.x*128 + threadIdx.x;     // 0..1407 (pixel pairs)
    int y = gid / 44;
    int x0 = (gid % 44) * 2;
    bool xm1 = (x0 > 0);
    bool xp2 = (x0 < 86);

    float a0[8], a1[8];
    #pragma unroll
    for (int j=0;j<8;j++) { a0[j] = b[co0+j]; a1[j] = b[co0+j]; }

    #pragma unroll 1
    for (int half=0; half<2; half++) {
        const int CC = half ? C2 : C1;
        if (CC == 0) continue;
        const float* src = half ? src2 : src1;
        const int ci_base = half ? C1 : 0;
        for (int ci=0; ci<CC; ci++) {
            const float* ip = src + (size_t)(n*CC+ci)*PIX;
            float tp[3][4];
            #pragma unroll
            for (int r=0;r<3;r++) {
                int yy = y-1+r;
                bool rv = ((unsigned)yy < FH);
                const float* rp = ip + yy*FW + x0;
                tp[r][0] = (rv && xm1) ? rp[-1] : 0.f;
                tp[r][1] = rv ? rp[0] : 0.f;
                tp[r][2] = rv ? rp[1] : 0.f;
                tp[r][3] = (rv && xp2) ? rp[2] : 0.f;
            }
            const float4* wq = (const float4*)(tw + (size_t)(ci_base+ci)*9*COUT + co0);
            #pragma unroll
            for (int r=0;r<3;r++) {
                #pragma unroll
                for (int c=0;c<3;c++) {
                    int k = r*3+c;
                    float4 wa = wq[k*(COUT/4)];
                    float4 wb = wq[k*(COUT/4)+1];
                    float ta = tp[r][c], tb = tp[r][c+1];
                    a0[0]=fmaf(ta,wa.x,a0[0]); a1[0]=fmaf(tb,wa.x,a1[0]);
                    a0[1]=fmaf(ta,wa.y,a0[1]); a1[1]=fmaf(tb,wa.y,a1[1]);
                    a0[2]=fmaf(ta,wa.z,a0[2]); a1[2]=fmaf(tb,wa.z,a1[2]);
                    a0[3]=fmaf(ta,wa.w,a0[3]); a1[3]=fmaf(tb,wa.w,a1[3]);
                    a0[4]=fmaf(ta,wb.x,a0[4]); a1[4]=fmaf(tb,wb.x,a1[4]);
                    a0[5]=fmaf(ta,wb.y,a0[5]); a1[5]=fmaf(tb,wb.y,a1[5]);
                    a0[6]=fmaf(ta,wb.z,a0[6]); a1[6]=fmaf(tb,wb.z,a1[6]);
                    a0[7]=fmaf(ta,wb.w,a0[7]); a1[7]=fmaf(tb,wb.w,a1[7]);
                }
            }
        }
    }
    int o = y*FW + x0;
    #pragma unroll
    for (int j=0;j<8;j++) {
        float* op = out + ((size_t)n*COUT + co0+j)*PIX + o;
        op[0] = fmaxf(fmaf(a0[j], s[co0+j], t[co0+j]), 0.f);
        op[1] = fmaxf(fmaf(a1[j], s[co0+j], t[co0+j]), 0.f);
    }
}

// dn3: 1x1 conv 256->139 + bias, 8 co per thread, weights [ci][144co]
__global__ __launch_bounds__(256) void k_dn3_v2(const float* __restrict__ in,
                                                const float* __restrict__ tw,
                                                const float* __restrict__ b,
                                                float* __restrict__ out) {
    int o = blockIdx.x*256 + threadIdx.x;       // 2816
    int n = blockIdx.z;
    int co0 = blockIdx.y*8;                      // 18 groups (144)
    const float* ip = in + (size_t)n*256*PIX + o;
    float acc[8];
    #pragma unroll
    for (int j=0;j<8;j++) acc[j]=0.f;
    for (int ci=0; ci<256; ci++) {
        float v = ip[(size_t)ci*PIX];
        const float4* wq = (const float4*)(tw + ci*144 + co0);
        float4 wa = wq[0], wb = wq[1];
        acc[0]=fmaf(v,wa.x,acc[0]); acc[1]=fmaf(v,wa.y,acc[1]);
        acc[2]=fmaf(v,wa.z,acc[2]); acc[3]=fmaf(v,wa.w,acc[3]);
        acc[4]=fmaf(v,wb.x,acc[4]); acc[5]=fmaf(v,wb.y,acc[5]);
        acc[6]=fmaf(v,wb.z,acc[6]); acc[7]=fmaf(v,wb.w,acc[7]);
    }
    #pragma unroll
    for (int j=0;j<8;j++) {
        int co = co0+j;
        if (co < 139) out[((size_t)n*139+co)*PIX + o] = acc[j] + b[co];
    }
}

// softmax over first 59 channels -> depth; copy 80 img feats -> featT [n*PIX, 80]
__global__ __launch_bounds__(256) void k_softmax_feat(const float* __restrict__ f3,
                                                      float* __restrict__ depth,
                                                      float* __restrict__ featT) {
    int o = blockIdx.x*256 + threadIdx.x;       // 16896
    int n = o / PIX, yx = o % PIX;
    const float* fp = f3 + (size_t)n*139*PIX + yx;
    float m = -1e30f;
    for (int d=0; d<DD; d++) m = fmaxf(m, fp[(size_t)d*PIX]);
    float sum = 0.f;
    for (int d=0; d<DD; d++) sum += expf(fp[(size_t)d*PIX]-m);
    float inv = 1.f/sum;
    for (int d=0; d<DD; d++)
        depth[((size_t)n*DD+d)*PIX + yx] = expf(fp[(size_t)d*PIX]-m)*inv;
    float* ft = featT + (size_t)o*CIMG;
    for (int c=0; c<CIMG; c++) ft[c] = fp[(size_t)(DD+c)*PIX];
}

// frustum -> lidar -> voxel index (or -1), + per-cell histogram
__global__ __launch_bounds__(256) void k_voxel(const float* __restrict__ mats, int* __restrict__ flat,
                                               int* __restrict__ cnt) {
    int p = blockIdx.x*256 + threadIdx.x;
    if (p >= NPTS) return;
    int x = p % FW; int t1 = p / FW;
    int y = t1 % FH; int t2 = t1 / FH;
    int dd = t2 % DD; int n = t2 / DD;
    float xf = x * (703.f/87.f);
    float yf = y * (255.f/31.f);
    float df = 1.f + (float)dd;
    const float* M = mats + n*24;
    float qx = M[0]*xf + M[1]*yf + M[2]*df + M[9];
    float qy = M[3]*xf + M[4]*yf + M[5]*df + M[10];
    float qz = M[6]*xf + M[7]*yf + M[8]*df + M[11];
    float rx = qx*qz, ry = qy*qz, rz = qz;
    float wx = M[12]*rx + M[13]*ry + M[14]*rz + M[21];
    float wy = M[15]*rx + M[16]*ry + M[17]*rz + M[22];
    float wz = M[18]*rx + M[19]*ry + M[20]*rz + M[23];
    int gx = (int)((wx + 54.f) / 0.3f);
    int gy = (int)((wy + 54.f) / 0.3f);
    int gz = (int)((wz + 10.f) / 20.f);
    bool kept = ((unsigned)gx < NXv) && ((unsigned)gy < NXv) && (gz == 0);
    int cell = kept ? (gx*NXv + gy) : -1;
    flat[p] = cell;
    if (kept) atomicAdd(&cnt[cell], 1);
}

// scan step 1: per-block (1024 cells) inclusive scan + block total
__global__ __launch_bounds__(256) void k_scan1(const int* __restrict__ cnt, int* __restrict__ incl,
                                               int* __restrict__ bsum) {
    int tid = threadIdx.x;
    int idx = blockIdx.x*1024 + tid*4;
    int c0 = (idx+0 < NCELLS) ? cnt[idx+0] : 0;
    int c1 = (idx+1 < NCELLS) ? cnt[idx+1] : 0;
    int c2 = (idx+2 < NCELLS) ? cnt[idx+2] : 0;
    int c3 = (idx+3 < NCELLS) ? cnt[idx+3] : 0;
    int s0=c0, s1=s0+c1, s2=s1+c2, s3=s2+c3;
    int v = s3;
    int lane = tid & 63, wid = tid >> 6;
    #pragma unroll
    for (int d=1; d<64; d<<=1) {
        int u = __shfl_up(v, d, 64);
        if (lane >= d) v += u;
    }
    __shared__ int wsum[4];
    if (lane == 63) wsum[wid] = v;
    __syncthreads();
    int woff = 0;
    #pragma unroll
    for (int w=0; w<3; w++) if (w < wid) woff += wsum[w];
    int texcl = woff + v - s3;
    if (idx+0 < NCELLS) incl[idx+0] = texcl + s0;
    if (idx+1 < NCELLS) incl[idx+1] = texcl + s1;
    if (idx+2 < NCELLS) incl[idx+2] = texcl + s2;
    if (idx+3 < NCELLS) incl[idx+3] = texcl + s3;
    if (tid == 255) bsum[blockIdx.x] = woff + v;
}

// scan step 2: exclusive scan of NB block sums (single wave, 2/lane)
__global__ void k_scan2(const int* __restrict__ bsum, int* __restrict__ bsx) {
    int lane = threadIdx.x;   // 64
    int a = (2*lane   < NB) ? bsum[2*lane]   : 0;
    int b = (2*lane+1 < NB) ? bsum[2*lane+1] : 0;
    int s = a + b;
    int v = s;
    #pragma unroll
    for (int d=1; d<64; d<<=1) {
        int u = __shfl_up(v, d, 64);
        if (lane >= d) v += u;
    }
    int excl = v - s;
    if (2*lane   < NB) bsx[2*lane]   = excl;
    if (2*lane+1 < NB) bsx[2*lane+1] = excl + a;
}

// scan step 3: exclusive offsets = incl - cnt + block base; also seed cursor
__global__ __launch_bounds__(256) void k_scan3(const int* __restrict__ incl, const int* __restrict__ cnt,
                                               const int* __restrict__ bsx, int* __restrict__ offs,
                                               int* __restrict__ cursor) {
    int idx = blockIdx.x*1024 + threadIdx.x*4;
    int o = bsx[blockIdx.x];
    #pragma unroll
    for (int j=0;j<4;j++) {
        if (idx+j < NCELLS) {
            int e = o + incl[idx+j] - cnt[idx+j];
            offs[idx+j] = e;
            cursor[idx+j] = e;
        }
    }
}

// bucket point ids into cell-sorted order
__global__ __launch_bounds__(256) void k_fill(const int* __restrict__ flat, int* __restrict__ cursor,
                                              int* __restrict__ order) {
    int p = blockIdx.x*256 + threadIdx.x;
    if (p >= NPTS) return;
    int cell = flat[p];
    if (cell < 0) return;
    int pos = atomicAdd(&cursor[cell], 1);
    order[pos] = p;
}

// gather segment-sum: one wave per cell, lanes = channels. No atomics.
__global__ __launch_bounds__(256) void k_gather(const int* __restrict__ offs, const int* __restrict__ cnt,
                                                const int* __restrict__ order,
                                                const float* __restrict__ depth,
                                                const float* __restrict__ featT,
                                                float* __restrict__ pooled) {
    int lane = threadIdx.x & 63;
    int cell = blockIdx.x*4 + (threadIdx.x >> 6);
    if (cell >= NCELLS) return;
    int k = cnt[cell], base = offs[cell];
    float acc0 = 0.f, acc1 = 0.f;
    for (int i=0; i<k; i++) {
        int p = order[base + i];
        float dv = depth[p];
        int n = p / (DD*PIX);
        int yx = p % PIX;
        const float* fr = featT + ((size_t)n*PIX + yx)*CIMG;
        acc0 = fmaf(dv, fr[lane], acc0);
        if (lane < 16) acc1 = fmaf(dv, fr[64+lane], acc1);
    }
    float* dst = pooled + (size_t)cell*CIMG;
    dst[lane] = acc0;
    if (lane < 16) dst[64+lane] = acc1;
}

// downsample convs on NHWC, weights pre-transposed to [tap, ci, co]
template<int STRIDE, int HIN, int HOUT, bool NCHW_OUT>
__global__ __launch_bounds__(320) void k_ds(const float* __restrict__ in,
                                            const float* __restrict__ tw,
                                            const float* __restrict__ s,
                                            const float* __restrict__ t,
                                            float* __restrict__ out) {
    int tid = threadIdx.x;            // 320 = 4 pixels x 80 co
    int j  = tid / CIMG;
    int co = tid % CIMG;
    int op = blockIdx.x*4 + j;        // HOUT*HOUT
    int xo = op / HOUT, yo = op % HOUT;
    float acc = 0.f;
    int xi0 = xo*STRIDE - 1, yi0 = yo*STRIDE - 1;
    #pragma unroll
    for (int kx=0;kx<3;kx++) {
        int xi = xi0+kx;
        if ((unsigned)xi >= HIN) continue;
        #pragma unroll
        for (int ky=0;ky<3;ky++) {
            int yi = yi0+ky;
            if ((unsigned)yi >= HIN) continue;
            const float* ip = in + (size_t)(xi*HIN + yi)*CIMG;
            const float* wp = tw + (size_t)((kx*3+ky)*CIMG)*CIMG + co;
            for (int ci=0; ci<CIMG; ci++)
                acc = fmaf(ip[ci], wp[(size_t)ci*CIMG], acc);
        }
    }
    float r = fmaxf(fmaf(acc, s[co], t[co]), 0.f);
    if (NCHW_OUT) out[((size_t)co*HOUT + xo)*HOUT + yo] = r;
    else          out[((size_t)xo*HOUT + yo)*CIMG + co] = r;
}

// ---------------- host launcher ----------------
extern "C" void kernel_launch(void* const* d_in, const int* in_sizes, int n_in,
                              void* d_out, int out_size, void* d_ws, size_t ws_size,
                              hipStream_t stream) {
    const float* x_img  = (const float*)d_in[0];
    const float* dimg   = (const float*)d_in[1];
    const float* c2l_R  = (const float*)d_in[2];
    const float* c2l_t  = (const float*)d_in[3];
    const float* intr   = (const float*)d_in[4];
    const float* prot   = (const float*)d_in[5];
    const float* ptran  = (const float*)d_in[6];
    const float* dt1_w  = (const float*)d_in[7];
    const float* dt1_b  = (const float*)d_in[8];
    const float* dt1_s  = (const float*)d_in[9];
    const float* dt1_t  = (const float*)d_in[10];
    const float* dt2_w  = (const float*)d_in[11];
    const float* dt2_b  = (const float*)d_in[12];
    const float* dt2_s  = (const float*)d_in[13];
    const float* dt2_t  = (const float*)d_in[14];
    const float* dt3_w  = (const float*)d_in[15];
    const float* dt3_b  = (const float*)d_in[16];
    const float* dt3_s  = (const float*)d_in[17];
    const float* dt3_t  = (const float*)d_in[18];
    const float* dn1_w  = (const float*)d_in[19];
    const float* dn1_b  = (const float*)d_in[20];
    const float* dn1_s  = (const float*)d_in[21];
    const float* dn1_t  = (const float*)d_in[22];
    const float* dn2_w  = (const float*)d_in[23];
    const float* dn2_b  = (const float*)d_in[24];
    const float* dn2_s  = (const float*)d_in[25];
    const float* dn2_t  = (const float*)d_in[26];
    const float* dn3_w  = (const float*)d_in[27];
    const float* dn3_b  = (const float*)d_in[28];
    const float* ds1_w  = (const float*)d_in[29];
    const float* ds1_s  = (const float*)d_in[30];
    const float* ds1_t  = (const float*)d_in[31];
    const float* ds2_w  = (const float*)d_in[32];
    const float* ds2_s  = (const float*)d_in[33];
    const float* ds2_t  = (const float*)d_in[34];

    float* ws = (float*)d_ws;
    float* mats   = ws + OFF_MATS;
    float* tw1    = ws + OFF_TW1;
    float* tw2    = ws + OFF_TW2;
    float* h1     = ws + OFF_A;     // [6,8,256,704]
    float* f2     = ws + OFF_A;     // [6,256,32,88]
    float* pooled = ws + OFF_A;     // [360*360, 80]
    float* twd1   = ws + OFF_TWD1;  // [320,9,256]
    float* twd2   = ws + OFF_TWD2;  // [256,9,256]
    float* twd3   = ws + OFF_TWD3;  // [256,144]
    float* h2     = ws + OFF_B;     // [6,32,64,176]
    float* f3     = ws + OFF_B;     // [6,139,32,88]
    int*   cnt    = (int*)(ws + OFF_CNT);
    int*   incl   = (int*)(ws + OFF_INCL);
    int*   offs   = (int*)(ws + OFF_OFFS);
    int*   cursor = (int*)(ws + OFF_CURSOR);
    int*   bsum   = (int*)(ws + OFF_BSUM);
    int*   bsx    = (int*)(ws + OFF_BSX);
    int*   order  = (int*)(ws + OFF_ORDER);
    float* h3     = ws + OFF_C;     // [6,64,32,88]
    float* depth  = ws + OFF_C;     // [6,59,32,88]
    float* f1     = ws + OFF_D;     // [6,256,32,88]
    float* featT  = ws + OFF_FEATT; // [6*2816, 80]
    int*   flat   = (int*)(ws + OFF_FLAT);
    float* bev1   = ws + OFF_BEV1;  // [180*180, 80]
    float* outp   = (float*)d_out;  // [80,180,180]

    // prep
    k_cam_mats<<<1, 64, 0, stream>>>(prot, ptran, intr, c2l_R, c2l_t, mats);
    k_wtrans<<<225, 256, 0, stream>>>(ds1_w, tw1);
    k_wtrans<<<225, 256, 0, stream>>>(ds2_w, tw2);

    // dtransform
    k_dt1<<<4224, 256, 0, stream>>>(dimg, dt1_w, dt1_b, dt1_s, dt1_t, h1);
    k_dt2<<<dim3(44,8,NCAM), 256, 0, stream>>>(h1, dt2_w, dt2_b, dt2_s, dt2_t, h2);

    // h1 dead now -> transpose dn weights into its upper region
    k_wtrans_dn<320,256><<<2880, 256, 0, stream>>>(dn1_w, twd1);
    k_wtrans_dn<256,256><<<2304, 256, 0, stream>>>(dn2_w, twd2);
    k_wtrans_dn3<<<144, 256, 0, stream>>>(dn3_w, twd3);

    k_dt3<<<dim3(11,16,NCAM), 256, 0, stream>>>(h2, dt3_w, dt3_b, dt3_s, dt3_t, h3);

    // depthnet (register-blocked, transposed weights)
    k_conv3x3_v2<64,256,256><<<dim3(11,32,NCAM), 128, 0, stream>>>(h3, x_img, twd1, dn1_b, dn1_s, dn1_t, f1);
    k_conv3x3_v2<256,0,256><<<dim3(11,32,NCAM), 128, 0, stream>>>(f1, f1, twd2, dn2_b, dn2_s, dn2_t, f2);
    k_dn3_v2<<<dim3(11,18,NCAM), 256, 0, stream>>>(f2, twd3, dn3_b, f3);

    // softmax + feature transpose (last reader of f3 / SEG_B)
    k_softmax_feat<<<66, 256, 0, stream>>>(f3, depth, featT);

    // bev_pool: voxelize + histogram + scan + bucket + gather (no float atomics)
    hipMemsetAsync(cnt, 0, NCELLS*sizeof(int), stream);
    k_voxel<<<3894, 256, 0, stream>>>(mats, flat, cnt);
    k_scan1<<<NB, 256, 0, stream>>>(cnt, incl, bsum);
    k_scan2<<<1, 64, 0, stream>>>(bsum, bsx);
    k_scan3<<<NB, 256, 0, stream>>>(incl, cnt, bsx, offs, cursor);
    k_fill<<<3894, 256, 0, stream>>>(flat, cursor, order);
    k_gather<<<32400, 256, 0, stream>>>(offs, cnt, order, depth, featT, pooled);

    // downsample
    k_ds<2,360,180,false><<<8100, 320, 0, stream>>>(pooled, tw1, ds1_s, ds1_t, bev1);
    k_ds<1,180,180,true><<<8100, 320, 0, stream>>>(bev1, tw2, ds2_s, ds2_t, outp);
}